// Round 1
// baseline (560.479 us; speedup 1.0000x reference)
//
#include <hip/hip_runtime.h>

typedef __attribute__((ext_vector_type(8))) short short8;
typedef __attribute__((ext_vector_type(4))) float floatx4;
typedef __attribute__((ext_vector_type(4))) unsigned int uintx4;
typedef __attribute__((ext_vector_type(2))) unsigned int uintx2;
typedef __attribute__((ext_vector_type(4))) int intx4;
typedef __attribute__((ext_vector_type(4))) unsigned short ushortx4;

#define NN 8192
#define KIN 512
#define COUT 256
#define SHIFT 16.0f

// ---------- helpers ----------
__device__ __forceinline__ unsigned int f2bf(float f) {
  unsigned int u = __float_as_uint(f);
  return (u + 0x7FFFu + ((u >> 16) & 1u)) >> 16;  // RNE round to bf16
}

__device__ __forceinline__ short8 pack8(const float* p) {
  uintx4 w;
  w.x = f2bf(p[0]) | (f2bf(p[1]) << 16);
  w.y = f2bf(p[2]) | (f2bf(p[3]) << 16);
  w.z = f2bf(p[4]) | (f2bf(p[5]) << 16);
  w.w = f2bf(p[6]) | (f2bf(p[7]) << 16);
  union { uintx4 u; short8 s; } cv; cv.u = w;
  return cv.s;
}

// ---------- K1a: cast input fp32 -> bf16 (row-major [8192][512]) ----------
__global__ void k_cast_input(const float* __restrict__ in, ushortx4* __restrict__ out) {
  int idx = blockIdx.x * 256 + threadIdx.x;          // 1048576 threads, 4 elems each
  floatx4 v = ((const floatx4*)in)[idx];
  ushortx4 o;
  o.x = (unsigned short)f2bf(v.x);
  o.y = (unsigned short)f2bf(v.y);
  o.z = (unsigned short)f2bf(v.z);
  o.w = (unsigned short)f2bf(v.w);
  out[idx] = o;
}

// ---------- K1b: weights [512][256] fp32 -> wt [256][512] bf16 (transposed) ----------
__global__ void k_prep_w(const float* __restrict__ w, unsigned short* __restrict__ wt) {
  int idx = blockIdx.x * 256 + threadIdx.x;          // 131072 threads
  int k = idx >> 8, c = idx & 255;
  wt[c * KIN + k] = (unsigned short)f2bf(w[idx]);
}

// ---------- K2: h = X*W via MFMA; emit ht[256][8192] bf16, e1[8192], e2[8192] ----------
// block = 256 thr = 4 waves; wave = 16 rows x 256 cols; grid = 128 (64 rows/block)
__global__ __launch_bounds__(256)
void k_gemm_h(const unsigned short* __restrict__ inA, const unsigned short* __restrict__ wt,
              const float* __restrict__ a1, const float* __restrict__ a2,
              unsigned short* __restrict__ ht, float* __restrict__ e1, float* __restrict__ e2) {
  int wave = threadIdx.x >> 6;
  int lane = threadIdx.x & 63;
  int n = lane & 15, q = lane >> 4;
  int row0 = blockIdx.x * 64 + wave * 16;            // wave's 16 rows
  int mrow = row0 + n;                               // this lane's A row

  floatx4 acc[16];
#pragma unroll
  for (int t = 0; t < 16; ++t) acc[t] = (floatx4){0.f, 0.f, 0.f, 0.f};

  for (int kc = 0; kc < KIN / 32; ++kc) {
    int k0 = kc * 32 + q * 8;
    short8 a = *(const short8*)(inA + (size_t)mrow * KIN + k0);
#pragma unroll
    for (int nt = 0; nt < 16; ++nt) {
      short8 b = *(const short8*)(wt + (size_t)(nt * 16 + n) * KIN + k0);
      acc[nt] = __builtin_amdgcn_mfma_f32_16x16x32_bf16(a, b, acc[nt], 0, 0, 0);
    }
  }

  // --- ht store: C/D layout col=lane&15, row=quad*4+reg; 4 regs = 4 consecutive i in ht[c][i]
  int i0 = row0 + q * 4;
#pragma unroll
  for (int nt = 0; nt < 16; ++nt) {
    int c = nt * 16 + n;
    uintx2 pk;
    pk.x = f2bf(acc[nt][0]) | (f2bf(acc[nt][1]) << 16);
    pk.y = f2bf(acc[nt][2]) | (f2bf(acc[nt][3]) << 16);
    *(uintx2*)(ht + (size_t)c * NN + i0) = pk;
  }

  // --- e1/e2 = h . a1 / h . a2 (fp32 acc), reduce across the 16 lanes of each quad
  float s1[4] = {0.f, 0.f, 0.f, 0.f}, s2[4] = {0.f, 0.f, 0.f, 0.f};
#pragma unroll
  for (int nt = 0; nt < 16; ++nt) {
    float w1 = a1[nt * 16 + n];
    float w2 = a2[nt * 16 + n];
#pragma unroll
    for (int r = 0; r < 4; ++r) {
      s1[r] += acc[nt][r] * w1;
      s2[r] += acc[nt][r] * w2;
    }
  }
#pragma unroll
  for (int m = 1; m < 16; m <<= 1) {
#pragma unroll
    for (int r = 0; r < 4; ++r) {
      s1[r] += __shfl_xor(s1[r], m);
      s2[r] += __shfl_xor(s2[r], m);
    }
  }
  if (n == 0) {
#pragma unroll
    for (int r = 0; r < 4; ++r) {
      e1[i0 + r] = s1[r];
      e2[i0 + r] = s2[r];
    }
  }
}

// ---------- K4: fused masked-softmax attention + PV ----------
// grid = 64 rowgroups x 8 j-slices = 512 blocks; block = 4 waves; wave = 32 rows x 256 cols
__global__ __launch_bounds__(256, 2)
void k_attn(const int* __restrict__ adj, const unsigned short* __restrict__ ht,
            const float* __restrict__ e1, const float* __restrict__ e2,
            float* __restrict__ out_num, float* __restrict__ Dbuf) {
  int b = blockIdx.x;
  int rg = b >> 3, js = b & 7;
  int wave = threadIdx.x >> 6, lane = threadIdx.x & 63;
  int n = lane & 15, q = lane >> 4;
  int rowbase = rg * 128 + wave * 32;

  float e1v0 = e1[rowbase + n];
  float e1v1 = e1[rowbase + 16 + n];

  floatx4 acc[2][16];
#pragma unroll
  for (int t = 0; t < 2; ++t)
#pragma unroll
    for (int nt = 0; nt < 16; ++nt) acc[t][nt] = (floatx4){0.f, 0.f, 0.f, 0.f};

  float d0 = 0.f, d1 = 0.f;
  int jbeg = js * 1024;

  for (int ch = 0; ch < 32; ++ch) {
    int j0 = jbeg + ch * 32 + q * 8;                 // this lane's 8 k positions
    floatx4 ea = *(const floatx4*)(e2 + j0);
    floatx4 eb = *(const floatx4*)(e2 + j0 + 4);
    float ev[8] = {ea.x, ea.y, ea.z, ea.w, eb.x, eb.y, eb.z, eb.w};

    intx4 A00 = *(const intx4*)(adj + (size_t)(rowbase + n) * NN + j0);
    intx4 A01 = *(const intx4*)(adj + (size_t)(rowbase + n) * NN + j0 + 4);
    intx4 A10 = *(const intx4*)(adj + (size_t)(rowbase + 16 + n) * NN + j0);
    intx4 A11 = *(const intx4*)(adj + (size_t)(rowbase + 16 + n) * NN + j0 + 4);

    float p0[8], p1[8];
#pragma unroll
    for (int jj = 0; jj < 8; ++jj) {
      int av0 = (jj < 4) ? A00[jj] : A01[jj - 4];
      int av1 = (jj < 4) ? A10[jj] : A11[jj - 4];
      float t0 = e1v0 + ev[jj];
      float t1 = e1v1 + ev[jj];
      float f0 = fmaxf(t0, 0.25f * t0);              // leakyrelu (slope 0.25)
      float f1 = fmaxf(t1, 0.25f * t1);
      float x0 = __expf(f0 - SHIFT);                 // fixed shift: exp <= ~0.14 always
      float x1 = __expf(f1 - SHIFT);
      p0[jj] = (av0 != 0) ? x0 : 0.f;
      p1[jj] = (av1 != 0) ? x1 : 0.f;
      d0 += p0[jj];
      d1 += p1[jj];
    }
    short8 af0 = pack8(p0);
    short8 af1 = pack8(p1);

#pragma unroll
    for (int g = 0; g < 2; ++g) {                    // two groups of 8 ntiles: caps live B-frags
      short8 bf[8];
#pragma unroll
      for (int t = 0; t < 8; ++t)
        bf[t] = *(const short8*)(ht + (size_t)((g * 8 + t) * 16 + n) * NN + j0);
#pragma unroll
      for (int t = 0; t < 8; ++t) {
        acc[0][g * 8 + t] = __builtin_amdgcn_mfma_f32_16x16x32_bf16(af0, bf[t], acc[0][g * 8 + t], 0, 0, 0);
        acc[1][g * 8 + t] = __builtin_amdgcn_mfma_f32_16x16x32_bf16(af1, bf[t], acc[1][g * 8 + t], 0, 0, 0);
      }
    }
  }

  // denominator: reduce across quads (lanes l, l^16, l^32, l^48 share the same row)
  d0 += __shfl_xor(d0, 16); d0 += __shfl_xor(d0, 32);
  d1 += __shfl_xor(d1, 16); d1 += __shfl_xor(d1, 32);
  if (lane < 16) {
    atomicAdd(Dbuf + rowbase + lane, d0);
    atomicAdd(Dbuf + rowbase + 16 + lane, d1);
  }

  // numerator: C/D layout col=lane&15, row=quad*4+reg
#pragma unroll
  for (int t2 = 0; t2 < 2; ++t2) {
#pragma unroll
    for (int nt = 0; nt < 16; ++nt) {
#pragma unroll
      for (int r = 0; r < 4; ++r) {
        int i = rowbase + t2 * 16 + q * 4 + r;
        atomicAdd(out_num + (size_t)i * COUT + nt * 16 + n, acc[t2][nt][r]);
      }
    }
  }
}

// ---------- K5: out = num/D + bias ----------
__global__ void k_final(float* __restrict__ out, const float* __restrict__ Dbuf,
                        const float* __restrict__ bias) {
  int idx = blockIdx.x * 256 + threadIdx.x;          // 2M threads
  int i = idx >> 8, c = idx & 255;
  float d = fmaxf(Dbuf[i], 1e-37f);
  out[idx] = out[idx] / d + bias[c];
}

// ---------- launch ----------
extern "C" void kernel_launch(void* const* d_in, const int* in_sizes, int n_in,
                              void* d_out, int out_size, void* d_ws, size_t ws_size,
                              hipStream_t stream) {
  const float* input   = (const float*)d_in[0];
  const int*   adj     = (const int*)d_in[1];
  const float* weights = (const float*)d_in[2];
  const float* a1      = (const float*)d_in[3];
  const float* a2      = (const float*)d_in[4];
  const float* bias    = (const float*)d_in[5];
  float* out = (float*)d_out;
  char* ws = (char*)d_ws;

  // ws layout (12.4 MB total)
  unsigned short* inA = (unsigned short*)(ws);                 // 8 MB   [8192][512] bf16
  unsigned short* wt  = (unsigned short*)(ws + 8388608);       // 256 KB [256][512] bf16
  unsigned short* ht  = (unsigned short*)(ws + 8650752);       // 4 MB   [256][8192] bf16
  float* e1   = (float*)(ws + 12845056);                       // 32 KB
  float* e2   = (float*)(ws + 12877824);                       // 32 KB
  float* Dbuf = (float*)(ws + 12910592);                       // 32 KB

  hipMemsetAsync(out, 0, (size_t)NN * COUT * sizeof(float), stream);
  hipMemsetAsync(Dbuf, 0, NN * sizeof(float), stream);

  k_cast_input<<<4096, 256, 0, stream>>>(input, (ushortx4*)inA);
  k_prep_w<<<512, 256, 0, stream>>>(weights, wt);
  k_gemm_h<<<128, 256, 0, stream>>>(inA, wt, a1, a2, ht, e1, e2);
  k_attn<<<512, 256, 0, stream>>>(adj, ht, e1, e2, out, Dbuf);
  k_final<<<8192, 256, 0, stream>>>(out, Dbuf, bias);
}

// Round 2
// 533.377 us; speedup vs baseline: 1.0508x; 1.0508x over previous
//
#include <hip/hip_runtime.h>

typedef __attribute__((ext_vector_type(8))) short short8;
typedef __attribute__((ext_vector_type(4))) float floatx4;
typedef __attribute__((ext_vector_type(4))) unsigned int uintx4;
typedef __attribute__((ext_vector_type(2))) unsigned int uintx2;
typedef __attribute__((ext_vector_type(4))) int intx4;
typedef __attribute__((ext_vector_type(4))) unsigned short ushortx4;

#define NN 8192
#define KIN 512
#define COUT 256
#define SHIFT 16.0f

// ---------- helpers ----------
__device__ __forceinline__ unsigned int f2bf(float f) {
  unsigned int u = __float_as_uint(f);
  return (u + 0x7FFFu + ((u >> 16) & 1u)) >> 16;  // RNE round to bf16
}

__device__ __forceinline__ short8 pack8(const float* p) {
  uintx4 w;
  w.x = f2bf(p[0]) | (f2bf(p[1]) << 16);
  w.y = f2bf(p[2]) | (f2bf(p[3]) << 16);
  w.z = f2bf(p[4]) | (f2bf(p[5]) << 16);
  w.w = f2bf(p[6]) | (f2bf(p[7]) << 16);
  union { uintx4 u; short8 s; } cv; cv.u = w;
  return cv.s;
}

// ---------- K1a: cast input fp32 -> bf16 (row-major [8192][512]) ----------
__global__ void k_cast_input(const float* __restrict__ in, ushortx4* __restrict__ out) {
  int idx = blockIdx.x * 256 + threadIdx.x;
  floatx4 v = ((const floatx4*)in)[idx];
  ushortx4 o;
  o.x = (unsigned short)f2bf(v.x);
  o.y = (unsigned short)f2bf(v.y);
  o.z = (unsigned short)f2bf(v.z);
  o.w = (unsigned short)f2bf(v.w);
  out[idx] = o;
}

// ---------- K1b: weights [512][256] fp32 -> wt [256][512] bf16 (transposed) ----------
__global__ void k_prep_w(const float* __restrict__ w, unsigned short* __restrict__ wt) {
  int idx = blockIdx.x * 256 + threadIdx.x;
  int k = idx >> 8, c = idx & 255;
  wt[c * KIN + k] = (unsigned short)f2bf(w[idx]);
}

// ---------- K2: h = X*W via MFMA; emit ht[256][8192] bf16, e1[8192], e2[8192] ----------
__global__ __launch_bounds__(256)
void k_gemm_h(const unsigned short* __restrict__ inA, const unsigned short* __restrict__ wt,
              const float* __restrict__ a1, const float* __restrict__ a2,
              unsigned short* __restrict__ ht, float* __restrict__ e1, float* __restrict__ e2) {
  int wave = threadIdx.x >> 6;
  int lane = threadIdx.x & 63;
  int n = lane & 15, q = lane >> 4;
  int row0 = blockIdx.x * 64 + wave * 16;
  int mrow = row0 + n;

  floatx4 acc[16];
#pragma unroll
  for (int t = 0; t < 16; ++t) acc[t] = (floatx4){0.f, 0.f, 0.f, 0.f};

  for (int kc = 0; kc < KIN / 32; ++kc) {
    int k0 = kc * 32 + q * 8;
    short8 a = *(const short8*)(inA + (size_t)mrow * KIN + k0);
#pragma unroll
    for (int nt = 0; nt < 16; ++nt) {
      short8 b = *(const short8*)(wt + (size_t)(nt * 16 + n) * KIN + k0);
      acc[nt] = __builtin_amdgcn_mfma_f32_16x16x32_bf16(a, b, acc[nt], 0, 0, 0);
    }
  }

  int i0 = row0 + q * 4;
#pragma unroll
  for (int nt = 0; nt < 16; ++nt) {
    int c = nt * 16 + n;
    uintx2 pk;
    pk.x = f2bf(acc[nt][0]) | (f2bf(acc[nt][1]) << 16);
    pk.y = f2bf(acc[nt][2]) | (f2bf(acc[nt][3]) << 16);
    *(uintx2*)(ht + (size_t)c * NN + i0) = pk;
  }

  float s1[4] = {0.f, 0.f, 0.f, 0.f}, s2[4] = {0.f, 0.f, 0.f, 0.f};
#pragma unroll
  for (int nt = 0; nt < 16; ++nt) {
    float w1 = a1[nt * 16 + n];
    float w2 = a2[nt * 16 + n];
#pragma unroll
    for (int r = 0; r < 4; ++r) {
      s1[r] += acc[nt][r] * w1;
      s2[r] += acc[nt][r] * w2;
    }
  }
#pragma unroll
  for (int m = 1; m < 16; m <<= 1) {
#pragma unroll
    for (int r = 0; r < 4; ++r) {
      s1[r] += __shfl_xor(s1[r], m);
      s2[r] += __shfl_xor(s2[r], m);
    }
  }
  if (n == 0) {
#pragma unroll
    for (int r = 0; r < 4; ++r) {
      e1[i0 + r] = s1[r];
      e2[i0 + r] = s2[r];
    }
  }
}

// ---------- K4 (partial-store version): masked-softmax attention + PV ----------
// grid = 64 rowgroups x 8 j-slices = 512 blocks; wave = 32 rows x 256 cols.
// Writes per-slice partials: opart[js][i][c], Dpart[js][i]. NO atomics.
__global__ __launch_bounds__(256, 2)
void k_attn_part(const int* __restrict__ adj, const unsigned short* __restrict__ ht,
                 const float* __restrict__ e1, const float* __restrict__ e2,
                 float* __restrict__ opart, float* __restrict__ Dpart) {
  int b = blockIdx.x;
  int rg = b >> 3, js = b & 7;
  int wave = threadIdx.x >> 6, lane = threadIdx.x & 63;
  int n = lane & 15, q = lane >> 4;
  int rowbase = rg * 128 + wave * 32;

  float e1v0 = e1[rowbase + n];
  float e1v1 = e1[rowbase + 16 + n];

  const int* rowp0 = adj + (size_t)(rowbase + n) * NN;
  const int* rowp1 = adj + (size_t)(rowbase + 16 + n) * NN;

  floatx4 acc[2][16];
#pragma unroll
  for (int t = 0; t < 2; ++t)
#pragma unroll
    for (int nt = 0; nt < 16; ++nt) acc[t][nt] = (floatx4){0.f, 0.f, 0.f, 0.f};

  float d0 = 0.f, d1 = 0.f;
  int jbeg = js * 1024;

  // prefetch chunk 0 adj
  int jp = jbeg + q * 8;
  intx4 A00 = *(const intx4*)(rowp0 + jp);
  intx4 A01 = *(const intx4*)(rowp0 + jp + 4);
  intx4 A10 = *(const intx4*)(rowp1 + jp);
  intx4 A11 = *(const intx4*)(rowp1 + jp + 4);

  for (int ch = 0; ch < 32; ++ch) {
    int j0 = jbeg + ch * 32 + q * 8;
    // issue next chunk's adj loads (wrap on last iter: harmless reload of chunk 0)
    int jn = jbeg + (((ch + 1) & 31) * 32) + q * 8;
    intx4 B00 = *(const intx4*)(rowp0 + jn);
    intx4 B01 = *(const intx4*)(rowp0 + jn + 4);
    intx4 B10 = *(const intx4*)(rowp1 + jn);
    intx4 B11 = *(const intx4*)(rowp1 + jn + 4);

    floatx4 ea = *(const floatx4*)(e2 + j0);
    floatx4 eb = *(const floatx4*)(e2 + j0 + 4);
    float ev[8] = {ea.x, ea.y, ea.z, ea.w, eb.x, eb.y, eb.z, eb.w};

    float p0[8], p1[8];
#pragma unroll
    for (int jj = 0; jj < 8; ++jj) {
      int av0 = (jj < 4) ? A00[jj] : A01[jj - 4];
      int av1 = (jj < 4) ? A10[jj] : A11[jj - 4];
      float t0 = e1v0 + ev[jj];
      float t1 = e1v1 + ev[jj];
      float f0 = fmaxf(t0, 0.25f * t0);              // leakyrelu
      float f1 = fmaxf(t1, 0.25f * t1);
      float x0 = __expf(f0 - SHIFT);
      float x1 = __expf(f1 - SHIFT);
      p0[jj] = (av0 != 0) ? x0 : 0.f;
      p1[jj] = (av1 != 0) ? x1 : 0.f;
      d0 += p0[jj];
      d1 += p1[jj];
    }
    short8 af0 = pack8(p0);
    short8 af1 = pack8(p1);

#pragma unroll
    for (int g = 0; g < 2; ++g) {
      short8 bf[8];
#pragma unroll
      for (int t = 0; t < 8; ++t)
        bf[t] = *(const short8*)(ht + (size_t)((g * 8 + t) * 16 + n) * NN + j0);
#pragma unroll
      for (int t = 0; t < 8; ++t) {
        acc[0][g * 8 + t] = __builtin_amdgcn_mfma_f32_16x16x32_bf16(af0, bf[t], acc[0][g * 8 + t], 0, 0, 0);
        acc[1][g * 8 + t] = __builtin_amdgcn_mfma_f32_16x16x32_bf16(af1, bf[t], acc[1][g * 8 + t], 0, 0, 0);
      }
    }

    A00 = B00; A01 = B01; A10 = B10; A11 = B11;
  }

  // denominator: reduce across quads then plain store
  d0 += __shfl_xor(d0, 16); d0 += __shfl_xor(d0, 32);
  d1 += __shfl_xor(d1, 16); d1 += __shfl_xor(d1, 32);
  if (lane < 16) {
    Dpart[(size_t)js * NN + rowbase + lane] = d0;
    Dpart[(size_t)js * NN + rowbase + 16 + lane] = d1;
  }

  // numerator partials: plain coalesced stores (4 rows x 16 consecutive floats per instr)
  float* op = opart + (size_t)js * NN * COUT;
#pragma unroll
  for (int t2 = 0; t2 < 2; ++t2) {
#pragma unroll
    for (int nt = 0; nt < 16; ++nt) {
#pragma unroll
      for (int r = 0; r < 4; ++r) {
        int i = rowbase + t2 * 16 + q * 4 + r;
        op[(size_t)i * COUT + nt * 16 + n] = acc[t2][nt][r];
      }
    }
  }
}

// ---------- K5 (partial-reduce): out = (sum_js opart)/ (sum_js Dpart) + bias ----------
__global__ void k_final_part(float* __restrict__ out, const float* __restrict__ opart,
                             const float* __restrict__ Dpart, const float* __restrict__ bias) {
  int i = blockIdx.x;
  int c = threadIdx.x;
  float s = 0.f, d = 0.f;
#pragma unroll
  for (int js = 0; js < 8; ++js) {
    s += opart[((size_t)js * NN + i) * COUT + c];
    d += Dpart[(size_t)js * NN + i];
  }
  out[(size_t)i * COUT + c] = s / fmaxf(d, 1e-37f) + bias[c];
}

// ---------- Fallback path (atomics) if ws is too small ----------
__global__ __launch_bounds__(256, 2)
void k_attn_atomic(const int* __restrict__ adj, const unsigned short* __restrict__ ht,
                   const float* __restrict__ e1, const float* __restrict__ e2,
                   float* __restrict__ out_num, float* __restrict__ Dbuf) {
  int b = blockIdx.x;
  int rg = b >> 3, js = b & 7;
  int wave = threadIdx.x >> 6, lane = threadIdx.x & 63;
  int n = lane & 15, q = lane >> 4;
  int rowbase = rg * 128 + wave * 32;

  float e1v0 = e1[rowbase + n];
  float e1v1 = e1[rowbase + 16 + n];

  floatx4 acc[2][16];
#pragma unroll
  for (int t = 0; t < 2; ++t)
#pragma unroll
    for (int nt = 0; nt < 16; ++nt) acc[t][nt] = (floatx4){0.f, 0.f, 0.f, 0.f};

  float d0 = 0.f, d1 = 0.f;
  int jbeg = js * 1024;

  for (int ch = 0; ch < 32; ++ch) {
    int j0 = jbeg + ch * 32 + q * 8;
    floatx4 ea = *(const floatx4*)(e2 + j0);
    floatx4 eb = *(const floatx4*)(e2 + j0 + 4);
    float ev[8] = {ea.x, ea.y, ea.z, ea.w, eb.x, eb.y, eb.z, eb.w};

    intx4 A00 = *(const intx4*)(adj + (size_t)(rowbase + n) * NN + j0);
    intx4 A01 = *(const intx4*)(adj + (size_t)(rowbase + n) * NN + j0 + 4);
    intx4 A10 = *(const intx4*)(adj + (size_t)(rowbase + 16 + n) * NN + j0);
    intx4 A11 = *(const intx4*)(adj + (size_t)(rowbase + 16 + n) * NN + j0 + 4);

    float p0[8], p1[8];
#pragma unroll
    for (int jj = 0; jj < 8; ++jj) {
      int av0 = (jj < 4) ? A00[jj] : A01[jj - 4];
      int av1 = (jj < 4) ? A10[jj] : A11[jj - 4];
      float t0 = e1v0 + ev[jj];
      float t1 = e1v1 + ev[jj];
      float f0 = fmaxf(t0, 0.25f * t0);
      float f1 = fmaxf(t1, 0.25f * t1);
      float x0 = __expf(f0 - SHIFT);
      float x1 = __expf(f1 - SHIFT);
      p0[jj] = (av0 != 0) ? x0 : 0.f;
      p1[jj] = (av1 != 0) ? x1 : 0.f;
      d0 += p0[jj];
      d1 += p1[jj];
    }
    short8 af0 = pack8(p0);
    short8 af1 = pack8(p1);

#pragma unroll
    for (int g = 0; g < 2; ++g) {
      short8 bf[8];
#pragma unroll
      for (int t = 0; t < 8; ++t)
        bf[t] = *(const short8*)(ht + (size_t)((g * 8 + t) * 16 + n) * NN + j0);
#pragma unroll
      for (int t = 0; t < 8; ++t) {
        acc[0][g * 8 + t] = __builtin_amdgcn_mfma_f32_16x16x32_bf16(af0, bf[t], acc[0][g * 8 + t], 0, 0, 0);
        acc[1][g * 8 + t] = __builtin_amdgcn_mfma_f32_16x16x32_bf16(af1, bf[t], acc[1][g * 8 + t], 0, 0, 0);
      }
    }
  }

  d0 += __shfl_xor(d0, 16); d0 += __shfl_xor(d0, 32);
  d1 += __shfl_xor(d1, 16); d1 += __shfl_xor(d1, 32);
  if (lane < 16) {
    atomicAdd(Dbuf + rowbase + lane, d0);
    atomicAdd(Dbuf + rowbase + 16 + lane, d1);
  }

#pragma unroll
  for (int t2 = 0; t2 < 2; ++t2) {
#pragma unroll
    for (int nt = 0; nt < 16; ++nt) {
#pragma unroll
      for (int r = 0; r < 4; ++r) {
        int i = rowbase + t2 * 16 + q * 4 + r;
        atomicAdd(out_num + (size_t)i * COUT + nt * 16 + n, acc[t2][nt][r]);
      }
    }
  }
}

__global__ void k_final_atomic(float* __restrict__ out, const float* __restrict__ Dbuf,
                               const float* __restrict__ bias) {
  int idx = blockIdx.x * 256 + threadIdx.x;
  int i = idx >> 8, c = idx & 255;
  float d = fmaxf(Dbuf[i], 1e-37f);
  out[idx] = out[idx] / d + bias[c];
}

// ---------- launch ----------
extern "C" void kernel_launch(void* const* d_in, const int* in_sizes, int n_in,
                              void* d_out, int out_size, void* d_ws, size_t ws_size,
                              hipStream_t stream) {
  const float* input   = (const float*)d_in[0];
  const int*   adj     = (const int*)d_in[1];
  const float* weights = (const float*)d_in[2];
  const float* a1      = (const float*)d_in[3];
  const float* a2      = (const float*)d_in[4];
  const float* bias    = (const float*)d_in[5];
  float* out = (float*)d_out;
  char* ws = (char*)d_ws;

  // ws layout
  unsigned short* inA = (unsigned short*)(ws);                 // 8 MB   [8192][512] bf16
  unsigned short* wt  = (unsigned short*)(ws + 8388608);       // 256 KB [256][512] bf16
  unsigned short* ht  = (unsigned short*)(ws + 8650752);       // 4 MB   [256][8192] bf16
  float* e1    = (float*)(ws + 12845056);                      // 32 KB
  float* e2    = (float*)(ws + 12877824);                      // 32 KB
  float* Dpart = (float*)(ws + 12910592);                      // 256 KB [8][8192]
  float* opart = (float*)(ws + 13172736);                      // 64 MB  [8][8192][256]
  const size_t WS_NEEDED_PART = 13172736 + (size_t)8 * NN * COUT * 4;  // ~77 MB
  float* Dbuf = Dpart;                                         // fallback reuses (32 KB)

  k_cast_input<<<4096, 256, 0, stream>>>(input, (ushortx4*)inA);
  k_prep_w<<<512, 256, 0, stream>>>(weights, wt);
  k_gemm_h<<<128, 256, 0, stream>>>(inA, wt, a1, a2, ht, e1, e2);

  if (ws_size >= WS_NEEDED_PART) {
    k_attn_part<<<512, 256, 0, stream>>>(adj, ht, e1, e2, opart, Dpart);
    k_final_part<<<8192, 256, 0, stream>>>(out, opart, Dpart, bias);
  } else {
    hipMemsetAsync(out, 0, (size_t)NN * COUT * sizeof(float), stream);
    hipMemsetAsync(Dbuf, 0, NN * sizeof(float), stream);
    k_attn_atomic<<<512, 256, 0, stream>>>(adj, ht, e1, e2, out, Dbuf);
    k_final_atomic<<<8192, 256, 0, stream>>>(out, Dbuf, bias);
  }
}